// Round 3
// baseline (714.804 us; speedup 1.0000x reference)
//
#include <hip/hip_runtime.h>

// PMF rating prediction: out[p] = relu(dot(U[user_ids[p]], V[item_ids[p]])), D=64.
//
// Theory: the direct kernel (159us/dispatch, 498MB HBM fetch vs ~265MB
// compulsory) loses to L3 thrash on the 221MB randomly-ordered user-row
// working set. Fix: deterministic two-level counting sort of pairs into 512
// user-id-range buckets (2048 users = 512KB of rows each), then compute
// bucket-by-bucket so user-row reuse and DRAM row locality are recovered.
//
// R3 hardening after two container failures: NO global atomics anywhere,
// all blocks <=512 threads, no zero-init pass (all ws words written before
// read in stream order), bucket indices clamped, every scatter write
// in-bounds by construction and guarded. Falls back to the round-0 kernel
// when ws is too small.

constexpr int HIDDEN = 64;
constexpr int K = 4;               // pairs per 16-lane group
constexpr int MAX_BUCKETS = 512;   // user-id ranges; also max chunks
constexpr int BASE_CHUNK = 4096;   // pairs per sort chunk (grows if n large)

using uint = unsigned int;

// ---------------------------------------------------------------------------
// Fallback: round-0 kernel (419us harness), used when ws is too small.
// ---------------------------------------------------------------------------
__global__ __launch_bounds__(256) void pmf_dot_kernel(
    const float* __restrict__ user_emb,
    const float* __restrict__ item_emb,
    const int*   __restrict__ user_ids,
    const int*   __restrict__ item_ids,
    float*       __restrict__ out,
    int n_pairs)
{
    const int group  = (blockIdx.x * blockDim.x + threadIdx.x) >> 4;
    const int lane16 = threadIdx.x & 15;
    const int p0     = group * K;

    if (p0 + K <= n_pairs) {
        const int4 u4 = *reinterpret_cast<const int4*>(user_ids + p0);
        const int4 i4 = *reinterpret_cast<const int4*>(item_ids + p0);

        const float4* up0 = reinterpret_cast<const float4*>(user_emb + (size_t)u4.x * HIDDEN) + lane16;
        const float4* up1 = reinterpret_cast<const float4*>(user_emb + (size_t)u4.y * HIDDEN) + lane16;
        const float4* up2 = reinterpret_cast<const float4*>(user_emb + (size_t)u4.z * HIDDEN) + lane16;
        const float4* up3 = reinterpret_cast<const float4*>(user_emb + (size_t)u4.w * HIDDEN) + lane16;
        const float4* vp0 = reinterpret_cast<const float4*>(item_emb + (size_t)i4.x * HIDDEN) + lane16;
        const float4* vp1 = reinterpret_cast<const float4*>(item_emb + (size_t)i4.y * HIDDEN) + lane16;
        const float4* vp2 = reinterpret_cast<const float4*>(item_emb + (size_t)i4.z * HIDDEN) + lane16;
        const float4* vp3 = reinterpret_cast<const float4*>(item_emb + (size_t)i4.w * HIDDEN) + lane16;

        const float4 a0 = *up0, a1 = *up1, a2 = *up2, a3 = *up3;
        const float4 b0 = *vp0, b1 = *vp1, b2 = *vp2, b3 = *vp3;

        float d0 = a0.x * b0.x + a0.y * b0.y + a0.z * b0.z + a0.w * b0.w;
        float d1 = a1.x * b1.x + a1.y * b1.y + a1.z * b1.z + a1.w * b1.w;
        float d2 = a2.x * b2.x + a2.y * b2.y + a2.z * b2.z + a2.w * b2.w;
        float d3 = a3.x * b3.x + a3.y * b3.y + a3.z * b3.z + a3.w * b3.w;

        #pragma unroll
        for (int s = 1; s < 16; s <<= 1) {
            d0 += __shfl_xor(d0, s, 16);
            d1 += __shfl_xor(d1, s, 16);
            d2 += __shfl_xor(d2, s, 16);
            d3 += __shfl_xor(d3, s, 16);
        }

        if (lane16 == 0) {
            float4 r;
            r.x = d0 > 0.0f ? d0 : 0.0f;
            r.y = d1 > 0.0f ? d1 : 0.0f;
            r.z = d2 > 0.0f ? d2 : 0.0f;
            r.w = d3 > 0.0f ? d3 : 0.0f;
            *reinterpret_cast<float4*>(out + p0) = r;
        }
    } else if (p0 < n_pairs) {
        for (int p = p0; p < n_pairs; ++p) {
            const int uid = user_ids[p];
            const int iid = item_ids[p];
            const float4 a = *(reinterpret_cast<const float4*>(user_emb + (size_t)uid * HIDDEN) + lane16);
            const float4 b = *(reinterpret_cast<const float4*>(item_emb + (size_t)iid * HIDDEN) + lane16);
            float d = a.x * b.x + a.y * b.y + a.z * b.z + a.w * b.w;
            #pragma unroll
            for (int s = 1; s < 16; s <<= 1) d += __shfl_xor(d, s, 16);
            if (lane16 == 0) out[p] = d > 0.0f ? d : 0.0f;
        }
    }
}

// ---------------------------------------------------------------------------
// Pass A: per-chunk bucket histogram. One block per chunk, LDS counters only,
// plain (non-atomic) coalesced store of the 512 counts. No global atomics.
// ---------------------------------------------------------------------------
__global__ __launch_bounds__(256) void chunk_hist_kernel(
    const int* __restrict__ uids, uint* __restrict__ chunkhist,
    int n, int chunk, int shift)
{
    __shared__ uint h[MAX_BUCKETS];
    for (int i = threadIdx.x; i < MAX_BUCKETS; i += 256) h[i] = 0u;
    __syncthreads();
    const int start = blockIdx.x * chunk;
    const int end   = min(start + chunk, n);
    for (int i = start + threadIdx.x; i < end; i += 256) {
        const uint b = min(((uint)uids[i]) >> shift, (uint)(MAX_BUCKETS - 1));
        atomicAdd(&h[b], 1u);  // LDS atomic only
    }
    __syncthreads();
    for (int i = threadIdx.x; i < MAX_BUCKETS; i += 256)
        chunkhist[(size_t)blockIdx.x * MAX_BUCKETS + i] = h[i];
}

// ---------------------------------------------------------------------------
// Pass B: single 512-thread block. Thread b owns bucket b: serial prefix over
// chunks (coalesced across threads), block scan for bucket starts, then add
// starts back into the per-chunk bases. Deterministic, no atomics.
// ---------------------------------------------------------------------------
__global__ __launch_bounds__(MAX_BUCKETS) void scan_kernel(
    const uint* __restrict__ chunkhist, uint* __restrict__ chunkbase,
    uint* __restrict__ offsets, int nchunks)
{
    const int b = threadIdx.x;
    uint acc = 0u;
    for (int c = 0; c < nchunks; ++c) {
        chunkbase[(size_t)c * MAX_BUCKETS + b] = acc;
        acc += chunkhist[(size_t)c * MAX_BUCKETS + b];
    }
    __shared__ uint tmp[MAX_BUCKETS];
    tmp[b] = acc;
    __syncthreads();
    for (int d = 1; d < MAX_BUCKETS; d <<= 1) {
        uint v = (b >= d) ? tmp[b - d] : 0u;
        __syncthreads();
        tmp[b] += v;
        __syncthreads();
    }
    const uint start = b ? tmp[b - 1] : 0u;
    offsets[b] = start;
    if (b == MAX_BUCKETS - 1) offsets[MAX_BUCKETS] = tmp[b];
    for (int c = 0; c < nchunks; ++c)
        chunkbase[(size_t)c * MAX_BUCKETS + b] += start;
}

// ---------------------------------------------------------------------------
// Pass C: scatter into bucket order as {uid, iid, pair_idx, 0} (16B records).
// One block per chunk; slot ranges [base, base+count) are disjoint across
// (chunk, bucket) by construction, so only LDS atomics are needed.
// ---------------------------------------------------------------------------
__global__ __launch_bounds__(256) void scatter_kernel(
    const int* __restrict__ uids, const int* __restrict__ iids,
    const uint* __restrict__ chunkbase, int4* __restrict__ triples,
    int n, int chunk, int shift)
{
    __shared__ uint base[MAX_BUCKETS];
    __shared__ uint lcnt[MAX_BUCKETS];
    for (int i = threadIdx.x; i < MAX_BUCKETS; i += 256) {
        base[i] = chunkbase[(size_t)blockIdx.x * MAX_BUCKETS + i];
        lcnt[i] = 0u;
    }
    __syncthreads();
    const int start = blockIdx.x * chunk;
    const int end   = min(start + chunk, n);
    for (int i = start + threadIdx.x; i < end; i += 256) {
        const int u = uids[i];
        const int v = iids[i];
        const uint b = min(((uint)u) >> shift, (uint)(MAX_BUCKETS - 1));
        const uint slot = base[b] + atomicAdd(&lcnt[b], 1u);  // LDS atomic
        if (slot < (uint)n)   // always true; belt-and-braces
            triples[slot] = make_int4(u, v, i, 0);
    }
}

// ---------------------------------------------------------------------------
// Pass D: binned compute. 4 blocks x 256 threads per bucket (64 groups of 16
// lanes, K=4 pairs each -> 8 float4 gathers in flight per thread). A bucket's
// user rows span one contiguous 512KB window -> reuse hits cache and the
// device-wide live user set equals the ~221MB compulsory bytes (L3-fits).
// ---------------------------------------------------------------------------
__global__ __launch_bounds__(256) void pmf_binned_kernel(
    const float* __restrict__ user_emb,
    const float* __restrict__ item_emb,
    const uint*  __restrict__ offsets,
    const int4*  __restrict__ triples,
    float*       __restrict__ out)
{
    const int bucket = blockIdx.x >> 2;
    const uint s = offsets[bucket];
    const uint e = offsets[bucket + 1];
    const int lane16 = threadIdx.x & 15;
    const int g = ((blockIdx.x & 3) << 4) | (threadIdx.x >> 4);  // 0..63

    for (uint q = s + (uint)g * 4u; q < e; q += 256u) {
        uint idx = q + (uint)(lane16 & 3);
        if (idx >= e) idx = e - 1;          // q<e so e>=1; clamp, masked at store
        const int4 t = triples[idx];        // lanes 0-3 hold the 4 pairs

        const int u0 = __shfl(t.x, 0, 16), i0 = __shfl(t.y, 0, 16);
        const int u1 = __shfl(t.x, 1, 16), i1 = __shfl(t.y, 1, 16);
        const int u2 = __shfl(t.x, 2, 16), i2 = __shfl(t.y, 2, 16);
        const int u3 = __shfl(t.x, 3, 16), i3 = __shfl(t.y, 3, 16);

        const float4* up0 = reinterpret_cast<const float4*>(user_emb + (size_t)u0 * HIDDEN) + lane16;
        const float4* up1 = reinterpret_cast<const float4*>(user_emb + (size_t)u1 * HIDDEN) + lane16;
        const float4* up2 = reinterpret_cast<const float4*>(user_emb + (size_t)u2 * HIDDEN) + lane16;
        const float4* up3 = reinterpret_cast<const float4*>(user_emb + (size_t)u3 * HIDDEN) + lane16;
        const float4* vp0 = reinterpret_cast<const float4*>(item_emb + (size_t)i0 * HIDDEN) + lane16;
        const float4* vp1 = reinterpret_cast<const float4*>(item_emb + (size_t)i1 * HIDDEN) + lane16;
        const float4* vp2 = reinterpret_cast<const float4*>(item_emb + (size_t)i2 * HIDDEN) + lane16;
        const float4* vp3 = reinterpret_cast<const float4*>(item_emb + (size_t)i3 * HIDDEN) + lane16;

        // Issue all 8 gathers before any use so they overlap.
        const float4 a0 = *up0, a1 = *up1, a2 = *up2, a3 = *up3;
        const float4 b0 = *vp0, b1 = *vp1, b2 = *vp2, b3 = *vp3;

        float d0 = a0.x * b0.x + a0.y * b0.y + a0.z * b0.z + a0.w * b0.w;
        float d1 = a1.x * b1.x + a1.y * b1.y + a1.z * b1.z + a1.w * b1.w;
        float d2 = a2.x * b2.x + a2.y * b2.y + a2.z * b2.z + a2.w * b2.w;
        float d3 = a3.x * b3.x + a3.y * b3.y + a3.z * b3.z + a3.w * b3.w;

        #pragma unroll
        for (int sft = 1; sft < 16; sft <<= 1) {
            d0 += __shfl_xor(d0, sft, 16);
            d1 += __shfl_xor(d1, sft, 16);
            d2 += __shfl_xor(d2, sft, 16);
            d3 += __shfl_xor(d3, sft, 16);
        }

        // Lanes 0-3 each hold their own pair's triple (t.z = original index).
        if (lane16 < 4 && (q + (uint)lane16) < e) {
            const float d = lane16 == 0 ? d0 : lane16 == 1 ? d1 : lane16 == 2 ? d2 : d3;
            out[t.z] = d > 0.0f ? d : 0.0f;
        }
    }
}

// ---------------------------------------------------------------------------
extern "C" void kernel_launch(void* const* d_in, const int* in_sizes, int n_in,
                              void* d_out, int out_size, void* d_ws, size_t ws_size,
                              hipStream_t stream) {
    const float* user_emb = (const float*)d_in[0];
    const float* item_emb = (const float*)d_in[1];
    const int*   user_ids = (const int*)d_in[2];
    const int*   item_ids = (const int*)d_in[3];
    float* out = (float*)d_out;

    const int n_pairs = in_sizes[2];                 // 2,000,000

    // Bucket shift: 11 -> 2048 users/bucket covers uid < 512*2048 = 1,048,576.
    // Any misinterpretation of in_sizes[0] only makes buckets coarser; the
    // kernels additionally clamp the bucket index, so it is always in range.
    long long n_users = (long long)in_sizes[0] / HIDDEN;
    int shift = 11;
    while (n_users > 0 && (((n_users - 1) >> shift) >= MAX_BUCKETS)) ++shift;

    // Chunk size: <= MAX_BUCKETS chunks.
    int chunk = BASE_CHUNK;
    while ((n_pairs + chunk - 1) / chunk > MAX_BUCKETS) chunk <<= 1;
    const int nchunks = (n_pairs + chunk - 1) / chunk;

    // Workspace layout (no zero-init needed; every word written before read):
    //   [0, 4096)                        : offsets  uint[513] (+pad)
    //   [4096, 4096+1MB)                 : chunkhist uint[512*512]
    //   [4096+1MB, 4096+2MB)             : chunkbase uint[512*512]
    //   [4096+2MB, ...)                  : triples  int4[n_pairs]
    const size_t META = 4096 + 2ull * MAX_BUCKETS * MAX_BUCKETS * sizeof(uint);
    const size_t ws_need = META + (size_t)n_pairs * sizeof(int4);

    if (d_ws == nullptr || ws_size < ws_need || n_pairs < BASE_CHUNK) {
        // Fallback: round-0 direct kernel.
        const int threads = 256;
        const int pairs_per_block = (threads / 16) * K;  // 64 pairs/block
        const int blocks = (n_pairs + pairs_per_block - 1) / pairs_per_block;
        pmf_dot_kernel<<<blocks, threads, 0, stream>>>(
            user_emb, item_emb, user_ids, item_ids, out, n_pairs);
        return;
    }

    uint* offsets   = (uint*)d_ws;                                   // [513]
    uint* chunkhist = (uint*)((char*)d_ws + 4096);                   // [512*512]
    uint* chunkbase = chunkhist + (size_t)MAX_BUCKETS * MAX_BUCKETS; // [512*512]
    int4* triples   = (int4*)((char*)d_ws + META);                   // [n_pairs]

    chunk_hist_kernel<<<nchunks, 256, 0, stream>>>(
        user_ids, chunkhist, n_pairs, chunk, shift);
    scan_kernel<<<1, MAX_BUCKETS, 0, stream>>>(
        chunkhist, chunkbase, offsets, nchunks);
    scatter_kernel<<<nchunks, 256, 0, stream>>>(
        user_ids, item_ids, chunkbase, triples, n_pairs, chunk, shift);
    pmf_binned_kernel<<<MAX_BUCKETS * 4, 256, 0, stream>>>(
        user_emb, item_emb, offsets, triples, out);
}

// Round 4
// 493.011 us; speedup vs baseline: 1.4499x; 1.4499x over previous
//
#include <hip/hip_runtime.h>

// PMF rating prediction: out[p] = relu(dot(U[user_ids[p]], V[item_ids[p]])), D=64.
//
// Architecture: deterministic two-level counting sort of pairs into 512
// user-id-range buckets (2048 users = 512KB of rows each), then compute
// bucket-by-bucket so the 2x user-row reuse hits cache (221MB compulsory
// working set, L3-fits) instead of thrashing (498MB fetched by the direct
// kernel). No global atomics anywhere.
//
// R4 fix (from counters): round-3's scan_kernel was 227us -- a single block
// serially looping 489 chunks. Replaced by a parallel per-bucket scan
// (512 blocks x 512 threads, LDS Hillis-Steele over chunks) + one tiny
// bucket-total scan block; the bucket-start add is folded into the scatter.
// Also: sorted records packed to 8B (uid|iid|idx bitfields, widths derived
// from in_sizes at launch) halving scatter/binned record traffic, and int4
// id loads in the histogram.

constexpr int HIDDEN = 64;
constexpr int K = 4;               // pairs per 16-lane group
constexpr int MAX_BUCKETS = 512;   // user-id ranges; also max chunks
constexpr int BASE_CHUNK = 4096;   // pairs per sort chunk (grows if n large)

using uint = unsigned int;
using u64 = unsigned long long;

// ---------------------------------------------------------------------------
// Fallback: round-0 kernel (419us harness), used when ws/shape doesn't fit.
// ---------------------------------------------------------------------------
__global__ __launch_bounds__(256) void pmf_dot_kernel(
    const float* __restrict__ user_emb,
    const float* __restrict__ item_emb,
    const int*   __restrict__ user_ids,
    const int*   __restrict__ item_ids,
    float*       __restrict__ out,
    int n_pairs)
{
    const int group  = (blockIdx.x * blockDim.x + threadIdx.x) >> 4;
    const int lane16 = threadIdx.x & 15;
    const int p0     = group * K;

    if (p0 + K <= n_pairs) {
        const int4 u4 = *reinterpret_cast<const int4*>(user_ids + p0);
        const int4 i4 = *reinterpret_cast<const int4*>(item_ids + p0);

        const float4* up0 = reinterpret_cast<const float4*>(user_emb + (size_t)u4.x * HIDDEN) + lane16;
        const float4* up1 = reinterpret_cast<const float4*>(user_emb + (size_t)u4.y * HIDDEN) + lane16;
        const float4* up2 = reinterpret_cast<const float4*>(user_emb + (size_t)u4.z * HIDDEN) + lane16;
        const float4* up3 = reinterpret_cast<const float4*>(user_emb + (size_t)u4.w * HIDDEN) + lane16;
        const float4* vp0 = reinterpret_cast<const float4*>(item_emb + (size_t)i4.x * HIDDEN) + lane16;
        const float4* vp1 = reinterpret_cast<const float4*>(item_emb + (size_t)i4.y * HIDDEN) + lane16;
        const float4* vp2 = reinterpret_cast<const float4*>(item_emb + (size_t)i4.z * HIDDEN) + lane16;
        const float4* vp3 = reinterpret_cast<const float4*>(item_emb + (size_t)i4.w * HIDDEN) + lane16;

        const float4 a0 = *up0, a1 = *up1, a2 = *up2, a3 = *up3;
        const float4 b0 = *vp0, b1 = *vp1, b2 = *vp2, b3 = *vp3;

        float d0 = a0.x * b0.x + a0.y * b0.y + a0.z * b0.z + a0.w * b0.w;
        float d1 = a1.x * b1.x + a1.y * b1.y + a1.z * b1.z + a1.w * b1.w;
        float d2 = a2.x * b2.x + a2.y * b2.y + a2.z * b2.z + a2.w * b2.w;
        float d3 = a3.x * b3.x + a3.y * b3.y + a3.z * b3.z + a3.w * b3.w;

        #pragma unroll
        for (int s = 1; s < 16; s <<= 1) {
            d0 += __shfl_xor(d0, s, 16);
            d1 += __shfl_xor(d1, s, 16);
            d2 += __shfl_xor(d2, s, 16);
            d3 += __shfl_xor(d3, s, 16);
        }

        if (lane16 == 0) {
            float4 r;
            r.x = d0 > 0.0f ? d0 : 0.0f;
            r.y = d1 > 0.0f ? d1 : 0.0f;
            r.z = d2 > 0.0f ? d2 : 0.0f;
            r.w = d3 > 0.0f ? d3 : 0.0f;
            *reinterpret_cast<float4*>(out + p0) = r;
        }
    } else if (p0 < n_pairs) {
        for (int p = p0; p < n_pairs; ++p) {
            const int uid = user_ids[p];
            const int iid = item_ids[p];
            const float4 a = *(reinterpret_cast<const float4*>(user_emb + (size_t)uid * HIDDEN) + lane16);
            const float4 b = *(reinterpret_cast<const float4*>(item_emb + (size_t)iid * HIDDEN) + lane16);
            float d = a.x * b.x + a.y * b.y + a.z * b.z + a.w * b.w;
            #pragma unroll
            for (int s = 1; s < 16; s <<= 1) d += __shfl_xor(d, s, 16);
            if (lane16 == 0) out[p] = d > 0.0f ? d : 0.0f;
        }
    }
}

// ---------------------------------------------------------------------------
// Pass A: per-chunk bucket histogram. One block per chunk, LDS counters only,
// int4 vector id loads, coalesced plain store of the 512 counts.
// ---------------------------------------------------------------------------
__global__ __launch_bounds__(256) void chunk_hist_kernel(
    const int* __restrict__ uids, uint* __restrict__ chunkhist,
    int n, int chunk, int shift)
{
    __shared__ uint h[MAX_BUCKETS];
    for (int i = threadIdx.x; i < MAX_BUCKETS; i += 256) h[i] = 0u;
    __syncthreads();
    const int start = blockIdx.x * chunk;
    const int end   = min(start + chunk, n);
    const int L     = end - start;
    const int L4    = L & ~3;
    for (int i = start + threadIdx.x * 4; i < start + L4; i += 1024) {
        const int4 u4 = *reinterpret_cast<const int4*>(uids + i);
        atomicAdd(&h[min(((uint)u4.x) >> shift, (uint)(MAX_BUCKETS - 1))], 1u);
        atomicAdd(&h[min(((uint)u4.y) >> shift, (uint)(MAX_BUCKETS - 1))], 1u);
        atomicAdd(&h[min(((uint)u4.z) >> shift, (uint)(MAX_BUCKETS - 1))], 1u);
        atomicAdd(&h[min(((uint)u4.w) >> shift, (uint)(MAX_BUCKETS - 1))], 1u);
    }
    for (int i = start + L4 + threadIdx.x; i < end; i += 256)
        atomicAdd(&h[min(((uint)uids[i]) >> shift, (uint)(MAX_BUCKETS - 1))], 1u);
    __syncthreads();
    for (int i = threadIdx.x; i < MAX_BUCKETS; i += 256)
        chunkhist[(size_t)blockIdx.x * MAX_BUCKETS + i] = h[i];
}

// ---------------------------------------------------------------------------
// Pass B1: parallel per-bucket prefix over chunks. Block b handles bucket b:
// thread t loads chunkhist[t][b] (one parallel load per thread), LDS
// Hillis-Steele scan, write exclusive prefix to chunkbase[t][b] and the
// bucket total to btotal[b]. 512 blocks -> fully parallel, ~1MB traffic.
// ---------------------------------------------------------------------------
__global__ __launch_bounds__(MAX_BUCKETS) void scanB1_kernel(
    const uint* __restrict__ chunkhist, uint* __restrict__ chunkbase,
    uint* __restrict__ btotal, int nchunks)
{
    __shared__ uint tmp[MAX_BUCKETS];
    const int b = blockIdx.x;
    const int t = threadIdx.x;
    const uint v = (t < nchunks) ? chunkhist[(size_t)t * MAX_BUCKETS + b] : 0u;
    tmp[t] = v;
    __syncthreads();
    #pragma unroll
    for (int d = 1; d < MAX_BUCKETS; d <<= 1) {
        const uint w = (t >= d) ? tmp[t - d] : 0u;
        __syncthreads();
        tmp[t] += w;
        __syncthreads();
    }
    if (t < nchunks)
        chunkbase[(size_t)t * MAX_BUCKETS + b] = tmp[t] - v;  // exclusive, no start
    if (t == MAX_BUCKETS - 1) btotal[b] = tmp[t];
}

// ---------------------------------------------------------------------------
// Pass B2: one block: exclusive scan of the 512 bucket totals -> offsets[513].
// ---------------------------------------------------------------------------
__global__ __launch_bounds__(MAX_BUCKETS) void scanB2_kernel(
    const uint* __restrict__ btotal, uint* __restrict__ offsets)
{
    __shared__ uint tmp[MAX_BUCKETS];
    const int t = threadIdx.x;
    tmp[t] = btotal[t];
    __syncthreads();
    #pragma unroll
    for (int d = 1; d < MAX_BUCKETS; d <<= 1) {
        const uint w = (t >= d) ? tmp[t - d] : 0u;
        __syncthreads();
        tmp[t] += w;
        __syncthreads();
    }
    offsets[t] = t ? tmp[t - 1] : 0u;
    if (t == MAX_BUCKETS - 1) offsets[MAX_BUCKETS] = tmp[t];
}

// ---------------------------------------------------------------------------
// Pass C: scatter into bucket order as packed 8B records
// rec = uid | iid<<bits_u | pair_idx<<(bits_u+bits_i).
// One block per chunk; slot ranges are disjoint by construction (chunk base +
// bucket start), so only LDS atomics are needed.
// ---------------------------------------------------------------------------
__global__ __launch_bounds__(256) void scatter_kernel(
    const int* __restrict__ uids, const int* __restrict__ iids,
    const uint* __restrict__ chunkbase, const uint* __restrict__ offsets,
    u64* __restrict__ recs, int n, int chunk, int shift, int bits_u, int bits_i)
{
    __shared__ uint base[MAX_BUCKETS];
    __shared__ uint lcnt[MAX_BUCKETS];
    for (int i = threadIdx.x; i < MAX_BUCKETS; i += 256) {
        base[i] = chunkbase[(size_t)blockIdx.x * MAX_BUCKETS + i] + offsets[i];
        lcnt[i] = 0u;
    }
    __syncthreads();
    const int start = blockIdx.x * chunk;
    const int end   = min(start + chunk, n);
    for (int i = start + threadIdx.x; i < end; i += 256) {
        const uint u = (uint)uids[i];
        const uint v = (uint)iids[i];
        const uint b = min(u >> shift, (uint)(MAX_BUCKETS - 1));
        const uint slot = base[b] + atomicAdd(&lcnt[b], 1u);  // LDS atomic
        if (slot < (uint)n)   // always true; belt-and-braces
            recs[slot] = (u64)u | ((u64)v << bits_u) | ((u64)(uint)i << (bits_u + bits_i));
    }
}

// ---------------------------------------------------------------------------
// Pass D: binned compute. 4 blocks x 256 threads per bucket (64 groups of 16
// lanes, K=4 pairs each -> 8 float4 gathers in flight per thread). A bucket's
// user rows span one contiguous 512KB window -> reuse hits cache and the
// device-wide live user set equals the ~221MB compulsory bytes (L3-fits).
// ---------------------------------------------------------------------------
__global__ __launch_bounds__(256) void pmf_binned_kernel(
    const float* __restrict__ user_emb,
    const float* __restrict__ item_emb,
    const uint*  __restrict__ offsets,
    const u64*   __restrict__ recs,
    float*       __restrict__ out,
    int bits_u, int bits_i)
{
    const int bucket = blockIdx.x >> 2;
    const uint s = offsets[bucket];
    const uint e = offsets[bucket + 1];
    const int lane16 = threadIdx.x & 15;
    const int g = ((blockIdx.x & 3) << 4) | (threadIdx.x >> 4);  // 0..63

    const u64 mu = ((u64)1 << bits_u) - 1;
    const u64 mi = ((u64)1 << bits_i) - 1;

    for (uint q = s + (uint)g * 4u; q < e; q += 256u) {
        uint idx = q + (uint)(lane16 & 3);
        if (idx >= e) idx = e - 1;          // q<e so e>=1; clamp, masked at store
        const u64 rec = recs[idx];          // lanes 0-3 hold the 4 pairs
        const int uu = (int)(rec & mu);
        const int vv = (int)((rec >> bits_u) & mi);

        const int u0 = __shfl(uu, 0, 16), i0 = __shfl(vv, 0, 16);
        const int u1 = __shfl(uu, 1, 16), i1 = __shfl(vv, 1, 16);
        const int u2 = __shfl(uu, 2, 16), i2 = __shfl(vv, 2, 16);
        const int u3 = __shfl(uu, 3, 16), i3 = __shfl(vv, 3, 16);

        const float4* up0 = reinterpret_cast<const float4*>(user_emb + (size_t)u0 * HIDDEN) + lane16;
        const float4* up1 = reinterpret_cast<const float4*>(user_emb + (size_t)u1 * HIDDEN) + lane16;
        const float4* up2 = reinterpret_cast<const float4*>(user_emb + (size_t)u2 * HIDDEN) + lane16;
        const float4* up3 = reinterpret_cast<const float4*>(user_emb + (size_t)u3 * HIDDEN) + lane16;
        const float4* vp0 = reinterpret_cast<const float4*>(item_emb + (size_t)i0 * HIDDEN) + lane16;
        const float4* vp1 = reinterpret_cast<const float4*>(item_emb + (size_t)i1 * HIDDEN) + lane16;
        const float4* vp2 = reinterpret_cast<const float4*>(item_emb + (size_t)i2 * HIDDEN) + lane16;
        const float4* vp3 = reinterpret_cast<const float4*>(item_emb + (size_t)i3 * HIDDEN) + lane16;

        // Issue all 8 gathers before any use so they overlap.
        const float4 a0 = *up0, a1 = *up1, a2 = *up2, a3 = *up3;
        const float4 b0 = *vp0, b1 = *vp1, b2 = *vp2, b3 = *vp3;

        float d0 = a0.x * b0.x + a0.y * b0.y + a0.z * b0.z + a0.w * b0.w;
        float d1 = a1.x * b1.x + a1.y * b1.y + a1.z * b1.z + a1.w * b1.w;
        float d2 = a2.x * b2.x + a2.y * b2.y + a2.z * b2.z + a2.w * b2.w;
        float d3 = a3.x * b3.x + a3.y * b3.y + a3.z * b3.z + a3.w * b3.w;

        #pragma unroll
        for (int sft = 1; sft < 16; sft <<= 1) {
            d0 += __shfl_xor(d0, sft, 16);
            d1 += __shfl_xor(d1, sft, 16);
            d2 += __shfl_xor(d2, sft, 16);
            d3 += __shfl_xor(d3, sft, 16);
        }

        // Lanes 0-3 each hold their own pair's record (idx = original index).
        if (lane16 < 4 && (q + (uint)lane16) < e) {
            const float d = lane16 == 0 ? d0 : lane16 == 1 ? d1 : lane16 == 2 ? d2 : d3;
            out[(uint)(rec >> (bits_u + bits_i))] = d > 0.0f ? d : 0.0f;
        }
    }
}

// ---------------------------------------------------------------------------
extern "C" void kernel_launch(void* const* d_in, const int* in_sizes, int n_in,
                              void* d_out, int out_size, void* d_ws, size_t ws_size,
                              hipStream_t stream) {
    const float* user_emb = (const float*)d_in[0];
    const float* item_emb = (const float*)d_in[1];
    const int*   user_ids = (const int*)d_in[2];
    const int*   item_ids = (const int*)d_in[3];
    float* out = (float*)d_out;

    const int n_pairs = in_sizes[2];                 // 2,000,000

    // Shape-derived constants (bench: 1M users, 100K items, 2M pairs).
    const long long n_users = (long long)in_sizes[0] / HIDDEN;
    const long long n_items = (long long)in_sizes[1] / HIDDEN;

    // Bucket shift: 11 -> 2048 users/bucket covers uid < 512*2048 = 1,048,576.
    // Kernels clamp the bucket index, so it is always in range regardless.
    int shift = 11;
    while (n_users > 0 && (((n_users - 1) >> shift) >= MAX_BUCKETS)) ++shift;

    // Packed-record bit widths.
    auto bits_for = [](long long v) { int b = 1; while ((1ll << b) < v) ++b; return b; };
    const int bits_u = bits_for(n_users > 1 ? n_users : 2);
    const int bits_i = bits_for(n_items > 1 ? n_items : 2);
    const int bits_p = bits_for(n_pairs > 1 ? n_pairs : 2);

    // Chunk size: <= MAX_BUCKETS chunks.
    int chunk = BASE_CHUNK;
    while ((n_pairs + chunk - 1) / chunk > MAX_BUCKETS) chunk <<= 1;
    const int nchunks = (n_pairs + chunk - 1) / chunk;

    // Workspace layout (every word written before read in stream order):
    //   [0, 4096)            : offsets uint[513] (+pad)
    //   [4096, 8192)         : btotal  uint[512] (+pad)
    //   [8192, 8192+1MB)     : chunkhist uint[512*512]
    //   [+1MB, +2MB)         : chunkbase uint[512*512]
    //   [+2MB, ...)          : recs u64[n_pairs]
    const size_t META = 8192 + 2ull * MAX_BUCKETS * MAX_BUCKETS * sizeof(uint);
    const size_t ws_need = META + (size_t)n_pairs * sizeof(u64);

    if (d_ws == nullptr || ws_size < ws_need || n_pairs < BASE_CHUNK ||
        bits_u + bits_i + bits_p > 64 || n_users <= 0 || n_items <= 0) {
        // Fallback: round-0 direct kernel.
        const int threads = 256;
        const int pairs_per_block = (threads / 16) * K;  // 64 pairs/block
        const int blocks = (n_pairs + pairs_per_block - 1) / pairs_per_block;
        pmf_dot_kernel<<<blocks, threads, 0, stream>>>(
            user_emb, item_emb, user_ids, item_ids, out, n_pairs);
        return;
    }

    uint* offsets   = (uint*)d_ws;                                   // [513]
    uint* btotal    = (uint*)((char*)d_ws + 4096);                   // [512]
    uint* chunkhist = (uint*)((char*)d_ws + 8192);                   // [512*512]
    uint* chunkbase = chunkhist + (size_t)MAX_BUCKETS * MAX_BUCKETS; // [512*512]
    u64*  recs      = (u64*)((char*)d_ws + META);                    // [n_pairs]

    chunk_hist_kernel<<<nchunks, 256, 0, stream>>>(
        user_ids, chunkhist, n_pairs, chunk, shift);
    scanB1_kernel<<<MAX_BUCKETS, MAX_BUCKETS, 0, stream>>>(
        chunkhist, chunkbase, btotal, nchunks);
    scanB2_kernel<<<1, MAX_BUCKETS, 0, stream>>>(btotal, offsets);
    scatter_kernel<<<nchunks, 256, 0, stream>>>(
        user_ids, item_ids, chunkbase, offsets, recs, n_pairs, chunk, shift,
        bits_u, bits_i);
    pmf_binned_kernel<<<MAX_BUCKETS * 4, 256, 0, stream>>>(
        user_emb, item_emb, offsets, recs, out, bits_u, bits_i);
}